// Round 17
// baseline (89.031 us; speedup 1.0000x reference)
//
#include <hip/hip_runtime.h>
#include <math.h>

#define B_ 8
#define N_ 4
#define D_ 256
#define HW_ 3072
#define A_ 256
#define NP_ 3              // view pairs (0,v), v=1..3
#define NJT2_ 48           // 3072 / 64-j partial granularity (gemm: 24 jt x 2)
#define NJB_ 96            // HW/32 = prep blocks per bn (vcnt partials)
#define INV_T 14.2857142857142857f  // 1/0.07
#define LDKH 64

typedef _Float16 half8 __attribute__((ext_vector_type(8)));
typedef _Float16 half2v __attribute__((ext_vector_type(2)));
typedef float f32x4 __attribute__((ext_vector_type(4)));
typedef unsigned uint2v __attribute__((ext_vector_type(2)));

// ---------------------------------------------------------------------------
// K1 (fused prep + nn as SEPARATE CONCURRENT BLOCKS; fusion proven r10):
//   ROUND-17: NORMALIZATION MOVED OUT OF PREP. sim = (a.b)*srnA*srnB exactly,
//   so prep now writes UNSCALED transposed fp16 straight from registers —
//   load -> convert -> store, NO tile LDS, NO swizzle, no barrier on the data
//   path (the two-phase load/LDS/barrier/re-read/scale/store structure shared
//   by all eight null probes is gone). Norms srn_g[bn][j] (view-0 rows
//   pre-multiplied by 1/T, same convention) are a 384 KB side output:
//   ssq chains + shfl reduce + ssql + one barrier + 32-thread finalize
//   (all formulas verbatim from the r15 proven body). Store pattern per
//   instruction: 8 x 64-B contiguous segments (lanes sharing jq write
//   consecutive d), same quality as the load side. Numerics: strictly fewer
//   roundings than before (drops the f16->f32->scale->f16 re-round).
//   blocks x>=96: NN search — r3 proven body verbatim, gid=(x-96)*32+y.
__global__ __launch_bounds__(256) void k_prep_nn(const float* __restrict__ f,
        const float* __restrict__ pts, _Float16* __restrict__ fh,
        float* __restrict__ srn_g,
        unsigned char* __restrict__ valid, int* __restrict__ vcnt_part,
        const int* __restrict__ aidx, int* __restrict__ pos_idx,
        unsigned char* __restrict__ valid_a, int* __restrict__ ticket) {
  __shared__ float ssql[4][8][4];
  int tid = threadIdx.x;

  if (blockIdx.x < 96) {
    // ------------------------- prep branch -------------------------
    int j0 = blockIdx.x * 32;
    int bn = blockIdx.y;
    int n = bn & 3;            // bn = b*N + n
    int jq = tid & 7;          // j-quad: j_local = 4*jq + {0..3}
    int dr = (tid >> 3) & 15;  // d-row group: rows 4*dr + {0..3} within dt
    int hh = tid >> 7;         // dt-pair half: dt = 2*hh + dtl

    f32x4 rv[2][4];
#pragma unroll
    for (int dtl = 0; dtl < 2; ++dtl) {
      int dt = 2 * hh + dtl;
      const float* fb = f + ((size_t)bn * D_ + dt * 64 + 4 * dr) * HW_ + j0 + 4 * jq;
      rv[dtl][0] = *(const f32x4*)&fb[0];
      rv[dtl][1] = *(const f32x4*)&fb[HW_];
      rv[dtl][2] = *(const f32x4*)&fb[2 * HW_];
      rv[dtl][3] = *(const f32x4*)&fb[3 * HW_];
    }

    // direct UNSCALED fp16 transpose writeout: r0..r3[jj] are consecutive d
    // (dt*64+4*dr+{0..3}) of row j=j0+4*jq+jj -> one 8-B dwordx2 per (dtl,jj)
#pragma unroll
    for (int dtl = 0; dtl < 2; ++dtl) {
      int dt = 2 * hh + dtl;
      f32x4 r0 = rv[dtl][0], r1 = rv[dtl][1], r2 = rv[dtl][2], r3 = rv[dtl][3];
#pragma unroll
      for (int jj = 0; jj < 4; ++jj) {
        half2v a, b2;
        a[0]  = (_Float16)r0[jj]; a[1]  = (_Float16)r1[jj];
        b2[0] = (_Float16)r2[jj]; b2[1] = (_Float16)r3[jj];
        uint2v w;
        w[0] = __builtin_bit_cast(unsigned, a);
        w[1] = __builtin_bit_cast(unsigned, b2);
        *(uint2v*)&fh[((size_t)bn * HW_ + j0 + 4 * jq + jj) * D_ + dt * 64 + 4 * dr] = w;
      }
    }

    // ssq accumulation (r15 verbatim chains)
    float ssq0 = 0.f, ssq1 = 0.f, ssq2 = 0.f, ssq3 = 0.f;
#pragma unroll
    for (int dtl = 0; dtl < 2; ++dtl) {
      f32x4 r0 = rv[dtl][0], r1 = rv[dtl][1], r2 = rv[dtl][2], r3 = rv[dtl][3];
      ssq0 = fmaf(r0[0], r0[0], fmaf(r1[0], r1[0], fmaf(r2[0], r2[0], fmaf(r3[0], r3[0], ssq0))));
      ssq1 = fmaf(r0[1], r0[1], fmaf(r1[1], r1[1], fmaf(r2[1], r2[1], fmaf(r3[1], r3[1], ssq1))));
      ssq2 = fmaf(r0[2], r0[2], fmaf(r1[2], r1[2], fmaf(r2[2], r2[2], fmaf(r3[2], r3[2], ssq2))));
      ssq3 = fmaf(r0[3], r0[3], fmaf(r1[3], r1[3], fmaf(r2[3], r2[3], fmaf(r3[3], r3[3], ssq3))));
    }
    // reduce over dr&7 within wave (r15 verbatim)
    ssq0 += __shfl_xor(ssq0, 8); ssq0 += __shfl_xor(ssq0, 16); ssq0 += __shfl_xor(ssq0, 32);
    ssq1 += __shfl_xor(ssq1, 8); ssq1 += __shfl_xor(ssq1, 16); ssq1 += __shfl_xor(ssq1, 32);
    ssq2 += __shfl_xor(ssq2, 8); ssq2 += __shfl_xor(ssq2, 16); ssq2 += __shfl_xor(ssq2, 32);
    ssq3 += __shfl_xor(ssq3, 8); ssq3 += __shfl_xor(ssq3, 16); ssq3 += __shfl_xor(ssq3, 32);
    if ((tid & 63) < 8) {
      int w = tid >> 6;        // w = (hh<<1) | (dr>>3): 4 partial groups
      ssql[w][jq][0] = ssq0; ssql[w][jq][1] = ssq1;
      ssql[w][jq][2] = ssq2; ssql[w][jq][3] = ssq3;
    }
    __syncthreads();
    if (tid < 32) {            // j = tid
      float s = ssql[0][tid >> 2][tid & 3] + ssql[1][tid >> 2][tid & 3]
              + ssql[2][tid >> 2][tid & 3] + ssql[3][tid >> 2][tid & 3];
      float r = 1.f / fmaxf(sqrtf(s), 1e-12f);
      size_t idx = (size_t)bn * HW_ + j0 + tid;
      srn_g[idx] = (n == 0) ? r * INV_T : r;
      const float* p = pts + idx * 3;
      float x = p[0], y = p[1], z = p[2];
      int v = (x * x + y * y + z * z) > 1e-12f ? 1 : 0;   // ||p|| > 1e-6
      valid[idx] = (unsigned char)v;
      unsigned long long mask = __ballot(v);
      if (tid == 0) vcnt_part[bn * NJB_ + blockIdx.x] = __popcll(mask);
    }
  } else {
    // ------------------------- nn branch (r3 body verbatim) ---------------
    int gid = (blockIdx.x - 96) * 32 + blockIdx.y;   // 0..1535
    if (gid == 0 && tid == 0) *ticket = 0;
    int wave = tid >> 6, lane = tid & 63;
    int agrp = gid & 63;
    int b = (gid >> 6) & 7;
    int p = gid >> 9;
    int a = agrp * 4 + wave;
    int vv = p + 1;
    int col = aidx[(p * B_ + b) * A_ + a];
    const float* pi = pts + ((size_t)(b * N_) * HW_ + col) * 3;
    float ax = pi[0], ay = pi[1], az = pi[2];
    int vi = (ax * ax + ay * ay + az * az) > 1e-12f ? 1 : 0;
    const f32x4* pj4 = (const f32x4*)(pts + (size_t)(b * N_ + vv) * HW_ * 3);
    float best = INFINITY; int bidx = 0x7fffffff;
#pragma unroll 2
    for (int t = 0; t < HW_ / 256; ++t) {      // 12 iterations
      int jb = t * 256 + lane * 4;
      int base = t * 192 + lane * 3;           // float4 index: (jb*3)/4
      f32x4 q0 = pj4[base + 0];
      f32x4 q1 = pj4[base + 1];
      f32x4 q2 = pj4[base + 2];
      float px[4] = {q0[0], q0[3], q1[2], q2[1]};
      float py[4] = {q0[1], q1[0], q1[3], q2[2]};
      float pz[4] = {q0[2], q1[1], q2[0], q2[3]};
#pragma unroll
      for (int k = 0; k < 4; ++k) {
        float x = px[k], y = py[k], z = pz[k];
        int vj = (x * x + y * y + z * z) > 1e-12f;
        float dx = ax - x, dy = ay - y, dz = az - z;
        float dist = sqrtf(dx * dx + dy * dy + dz * dz);
        int j = jb + k;
        if (vj && (dist < best || (dist == best && j < bidx))) { best = dist; bidx = j; }
      }
    }
#pragma unroll
    for (int o = 32; o > 0; o >>= 1) {
      float ob = __shfl_xor(best, o);
      int oi = __shfl_xor(bidx, o);
      if (ob < best || (ob == best && oi < bidx)) { best = ob; bidx = oi; }
    }
    if (lane == 0) {
      int ai = (p * B_ + b) * A_ + a;
      pos_idx[ai] = (bidx == 0x7fffffff) ? 0 : bidx;
      valid_a[ai] = (best < 0.1f) && vi;
    }
  }
}

// ---------------------------------------------------------------------------
// K3: MFMA f16 GEMM, 128x128 tile, 4 waves (2x2 of 64x64), BK=64, dbuf LDS,
// LDS-transpose epilogue (r6 structure). ROUND-17: inputs are UNSCALED fp16;
// the epilogue applies sim = acc * srnA[colA] * srnB[j] (srnA carries 1/T).
// Staging, K-loop, fragment layouts byte-identical to the proven body.
#define STAGE_AB(KK, BUF) do {                                                 \
  _Pragma("unroll")                                                            \
  for (int cc = 0; cc < 4; ++cc) {                                             \
    const _Float16* srcA = fA + (size_t)colA[cc] * D_ + (KK) * 64 + gsw * 8;   \
    __builtin_amdgcn_global_load_lds(                                          \
        (const __attribute__((address_space(1))) void*)srcA,                   \
        (__attribute__((address_space(3))) void*)&As[BUF][(wid * 32 + cc * 8) * LDKH], \
        16, 0, 0);                                                             \
  }                                                                            \
  _Pragma("unroll")                                                            \
  for (int cc = 0; cc < 4; ++cc) {                                             \
    const _Float16* srcB = fB + (size_t)rowB[cc] * D_ + (KK) * 64 + gsw * 8;   \
    __builtin_amdgcn_global_load_lds(                                          \
        (const __attribute__((address_space(1))) void*)srcB,                   \
        (__attribute__((address_space(3))) void*)&Bs[BUF][(wid * 32 + cc * 8) * LDKH], \
        16, 0, 0);                                                             \
  }                                                                            \
} while (0)

__global__ __launch_bounds__(256) void k_gemm(const _Float16* __restrict__ fh,
    const float* __restrict__ srn_g, const int* __restrict__ aidx,
    const unsigned char* __restrict__ valid, const int* __restrict__ pos_idx,
    float* __restrict__ possim, float2* __restrict__ partials) {
  __shared__ __align__(16) char smem[65536];
  _Float16 (*As)[128 * LDKH] = reinterpret_cast<_Float16 (*)[128 * LDKH]>(smem);
  _Float16 (*Bs)[128 * LDKH] = reinterpret_cast<_Float16 (*)[128 * LDKH]>(smem + 32768);
  float (*scr)[132] = reinterpret_cast<float (*)[132]>(smem);   // reused post-K-loop

  int jt = blockIdx.x;
  int pbm = blockIdx.y;          // 0..47: pb*2 + mt
  int pb = pbm >> 1, mt = pbm & 1;
  int b = pb & 7, p = pb >> 3, v = p + 1;
  int tid = threadIdx.x;
  int wid = tid >> 6, lane = tid & 63;   // 4 waves
  int wr = wid >> 1, wc = wid & 1;       // 2x2 of 64x64
  int j0 = jt * 128;
  const _Float16* fA = fh + (size_t)(b * N_) * HW_ * D_;        // view 0
  const _Float16* fB = fh + (size_t)(b * N_ + v) * HW_ * D_;    // view v

  // staging: lane -> (row offset rl = lane>>3, granule gl = lane&7),
  // source granule pre-swizzled: gsw = gl ^ rl = g ^ (row&7).
  int rl = lane >> 3;
  int gl = lane & 7;
  int gsw = gl ^ rl;
  int colA[4];
#pragma unroll
  for (int c = 0; c < 4; ++c)
    colA[c] = aidx[(p * B_ + b) * A_ + mt * 128 + wid * 32 + c * 8 + rl];
  int rowB[4];
#pragma unroll
  for (int c = 0; c < 4; ++c) rowB[c] = j0 + wid * 32 + c * 8 + rl;

  f32x4 acc[4][4];
#pragma unroll
  for (int m = 0; m < 4; ++m)
#pragma unroll
    for (int n = 0; n < 4; ++n) acc[m][n] = (f32x4)0.f;

  int kg = lane >> 4;        // k-granule 0..3
  int fr = lane & 15;        // fragment row

  STAGE_AB(0, 0);
  __syncthreads();           // drains vmcnt(0): buf0 ready

#pragma unroll
  for (int kk = 0; kk < 4; ++kk) {
    const int cur = kk & 1;
    if (kk < 3) STAGE_AB(kk + 1, cur ^ 1);   // issue-early: hides under MFMA
#pragma unroll
    for (int s = 0; s < 2; ++s) {
      half8 af[4], bf[4];
      int G = s * 4 + kg;
#pragma unroll
      for (int m = 0; m < 4; ++m) {
        int row = wr * 64 + m * 16 + fr;
        af[m] = *(half8*)&As[cur][row * LDKH + ((G ^ (row & 7)) << 3)];
      }
#pragma unroll
      for (int n = 0; n < 4; ++n) {
        int row = wc * 64 + n * 16 + fr;
        bf[n] = *(half8*)&Bs[cur][row * LDKH + ((G ^ (row & 7)) << 3)];
      }
      __builtin_amdgcn_s_setprio(1);
#pragma unroll
      for (int m = 0; m < 4; ++m)
#pragma unroll
        for (int n = 0; n < 4; ++n)
          acc[m][n] = __builtin_amdgcn_mfma_f32_16x16x32_f16(af[m], bf[n], acc[m][n], 0, 0, 0);
      __builtin_amdgcn_s_setprio(0);
    }
    if (kk < 3) __syncthreads();   // drains prefetch vmcnt; next buf ready
  }

  // ---- epilogue (LDS-transpose, sequential per-thread reduction) ----
  __syncthreads();   // all As/Bs reads retired -> LDS reusable as scratch

  int vrow = b * N_ + v;
  int a_loc = tid >> 1, h = tid & 1;          // anchor 0..127, j-half 0/1
  int aig = pb * A_ + mt * 128 + a_loc;
  int pidx = pos_idx[aig];
  // r17: per-anchor scale (srnA carries 1/T via view-0 convention)
  int colAe = aidx[(p * B_ + b) * A_ + mt * 128 + a_loc];
  float sA = srn_g[(size_t)(b * N_) * HW_ + colAe];

#pragma unroll
  for (int pss = 0; pss < 2; ++pss) {
    if (wc == pss) {
      // dump this wave's 64x64 acc tile: value (m,n,reg) is anchor
      // wr*64+m*16+kg*4+reg, local column n*16+fr within the pss 64-j half
#pragma unroll
      for (int m = 0; m < 4; ++m)
#pragma unroll
        for (int n = 0; n < 4; ++n)
          *(f32x4*)&scr[n * 16 + fr][wr * 64 + m * 16 + kg * 4] = acc[m][n];
    }
    __syncthreads();
    int jbase = j0 + pss * 64 + h * 32;
    const unsigned* vp = (const unsigned*)(valid + (size_t)vrow * HW_ + jbase);
    unsigned vw[8];
#pragma unroll
    for (int w = 0; w < 8; ++w) vw[w] = vp[w];
    // r17: per-j B-side scales (contiguous 128 B per thread)
    float sB[32];
#pragma unroll
    for (int q4 = 0; q4 < 8; ++q4)
      *(f32x4*)&sB[q4 * 4] = *(const f32x4*)&srn_g[(size_t)vrow * HW_ + jbase + q4 * 4];
    float vv[32];
#pragma unroll
    for (int jj = 0; jj < 32; ++jj)
      vv[jj] = scr[h * 32 + jj][a_loc] * sA * sB[jj];
    float mx = -INFINITY;
#pragma unroll
    for (int jj = 0; jj < 32; ++jj) {
      if ((vw[jj >> 2] >> ((jj & 3) * 8)) & 0xff) mx = fmaxf(mx, vv[jj]);
      if (jbase + jj == pidx) possim[aig] = vv[jj];
    }
    float S = 0.f;
#pragma unroll
    for (int jj = 0; jj < 32; ++jj) {
      if ((vw[jj >> 2] >> ((jj & 3) * 8)) & 0xff) S += __expf(vv[jj] - mx);
    }
    // merge the two 32-j halves of this anchor (partner thread = tid^1)
    float am = fmaxf(mx, __shfl_xor(mx, 1));
    float Ss = (mx == am) ? S : S * __expf(mx - am);
    Ss += __shfl_xor(Ss, 1);
    if (h == 0) partials[(size_t)aig * NJT2_ + (jt * 2 + pss)] = make_float2(am, Ss);
    __syncthreads();   // pass-1 reads done before pass-2 overwrites scratch
  }
}

// ---------------------------------------------------------------------------
// K4: merge partial LSEs (4 threads/anchor), per-(pair,batch) reduction +
// include; last block (device ticket) computes the final scalar. (r6 body;
// vcnt loops at NJB_=96)
__global__ __launch_bounds__(1024) void k_merge(const float2* __restrict__ partials,
    const float* __restrict__ possim, const unsigned char* __restrict__ valid_a,
    const int* __restrict__ vcnt_part, float* __restrict__ lossb,
    int* __restrict__ incb, int* __restrict__ ticket, float* __restrict__ out) {
  int pb = blockIdx.x;
  int b = pb & 7, p = pb >> 3;
  int tid = threadIdx.x;
  int a = tid >> 2, q = tid & 3;
  int ai = pb * A_ + a;

  __shared__ float ss[16]; __shared__ int sc[16];
  __shared__ int v0c, vvc;
  if (tid == 0) { v0c = 0; vvc = 0; }
  __syncthreads();
  if (tid < NJB_) atomicAdd(&v0c, vcnt_part[(b * N_ + 0) * NJB_ + tid]);
  else if (tid < 2 * NJB_) atomicAdd(&vvc, vcnt_part[(b * N_ + p + 1) * NJB_ + (tid - NJB_)]);

  // each thread: 12 (m,S) pairs = 6 float4, contiguous 96 B
  const float4* pt = (const float4*)partials + (size_t)ai * 24 + q * 6;
  float4 vv4[6];
#pragma unroll
  for (int i = 0; i < 6; ++i) vv4[i] = pt[i];
  float mx = -INFINITY;
#pragma unroll
  for (int i = 0; i < 6; ++i) { mx = fmaxf(mx, vv4[i].x); mx = fmaxf(mx, vv4[i].z); }
  float S = 0.f;
  if (mx != -INFINITY) {
#pragma unroll
    for (int i = 0; i < 6; ++i) {
      S += vv4[i].y * __expf(vv4[i].x - mx);
      S += vv4[i].w * __expf(vv4[i].z - mx);
    }
  }
  // merge across the 4 lanes of this anchor
  float am = mx;
#pragma unroll
  for (int o = 1; o < 4; o <<= 1) am = fmaxf(am, __shfl_xor(am, o));
  float Sg = S * ((mx == am) ? 1.f : __expf(mx - am));
#pragma unroll
  for (int o = 1; o < 4; o <<= 1) Sg += __shfl_xor(Sg, o);

  float contrib = 0.f; int cnt = 0;
  if (q == 0) {
    float lse = (am == -INFINITY) ? -INFINITY : am + logf(Sg);
    if (valid_a[ai]) { contrib = lse - possim[ai]; cnt = 1; }
  }
  // wave reduce (leads are lanes with (lane&3)==0)
#pragma unroll
  for (int o = 4; o < 64; o <<= 1) {
    contrib += __shfl_xor(contrib, o);
    cnt += __shfl_xor(cnt, o);
  }
  if ((tid & 63) == 0) { ss[tid >> 6] = contrib; sc[tid >> 6] = cnt; }
  __syncthreads();
  if (tid == 0) {
    float s = 0.f; int c = 0;
#pragma unroll
    for (int i = 0; i < 16; ++i) { s += ss[i]; c += sc[i]; }
    float lb = s / (float)(c > 1 ? c : 1);
    int inc = (c >= 5) && (v0c >= 10) && (vvc >= 10);
    lossb[pb] = lb;
    incb[pb] = inc;
    __threadfence();
    int old = atomicAdd(ticket, 1);
    if (old == NP_ * B_ - 1) {
      __threadfence();
      float total = 0.f;
      for (int pp = 0; pp < NP_; ++pp) {
        float sacc = 0.f; int n = 0;
        for (int bb = 0; bb < B_; ++bb)
          if (incb[pp * B_ + bb]) { sacc += lossb[pp * B_ + bb]; ++n; }
        total += (n > 0) ? sacc / (float)n : 0.f;
      }
      out[0] = total / (float)NP_;
    }
  }
}

// ---------------------------------------------------------------------------
extern "C" void kernel_launch(void* const* d_in, const int* in_sizes, int n_in,
                              void* d_out, int out_size, void* d_ws, size_t ws_size,
                              hipStream_t stream) {
  const float* f   = (const float*)d_in[0];   // [B,N,D,H,W] fp32
  const float* pts = (const float*)d_in[1];   // [B,N,H,W,3] fp32
  const int* aidx  = (const int*)d_in[2];     // [NP,B,A] int32
  float* out = (float*)d_out;

  char* ws = (char*)d_ws;
  _Float16* fh          = (_Float16*)(ws);                    // 32*3072*256*2 = 50,331,648
  unsigned char* valid  = (unsigned char*)(ws + 50331648);    // 98,304
  int* pos_idx          = (int*)(ws + 50429952);              // 24,576
  unsigned char* valid_a= (unsigned char*)(ws + 50454528);    // 6,144
  float* possim         = (float*)(ws + 50460672);            // 24,576
  float* lossb          = (float*)(ws + 50485248);            // 96 (pad to 128)
  int* incb             = (int*)(ws + 50485376);              // 96 (pad to 128)
  float2* partials      = (float2*)(ws + 50485504);           // 6144*48*8 = 2,359,296
  int* vcnt_part        = (int*)(ws + 52844800);              // 32*96*4 = 12,288
  int* ticket           = (int*)(ws + 52857088);              // 4 (pad to 128)
  float* srn_g          = (float*)(ws + 52857216);            // 32*3072*4 = 393,216
  // total ws usage: 53,250,432 bytes

  k_prep_nn<<<dim3(144, 32), 256, 0, stream>>>(f, pts, fh, srn_g, valid, vcnt_part,
                                               aidx, pos_idx, valid_a, ticket);
  k_gemm<<<dim3(24, NP_ * B_ * 2), 256, 0, stream>>>(fh, srn_g, aidx, valid, pos_idx,
                                                     possim, partials);
  k_merge<<<NP_ * B_, 1024, 0, stream>>>(partials, possim, valid_a, vcnt_part, lossb, incb, ticket, out);
}

// Round 18
// 83.730 us; speedup vs baseline: 1.0633x; 1.0633x over previous
//
#include <hip/hip_runtime.h>
#include <math.h>

#define B_ 8
#define N_ 4
#define D_ 256
#define HW_ 3072
#define A_ 256
#define NP_ 3              // view pairs (0,v), v=1..3
#define NJT2_ 48           // 3072 / 64-j partial granularity (gemm: 24 jt x 2)
#define NJB_ 96            // HW/32 = prep blocks per bn (vcnt partials)
#define INV_T 14.2857142857142857f  // 1/0.07
#define LDKH 64

typedef _Float16 half8 __attribute__((ext_vector_type(8)));
typedef _Float16 half2v __attribute__((ext_vector_type(2)));
typedef float f32x4 __attribute__((ext_vector_type(4)));
typedef unsigned uint2v __attribute__((ext_vector_type(2)));
typedef unsigned uint4v __attribute__((ext_vector_type(4)));

// ---------------------------------------------------------------------------
// FINAL (r16 state, session best 83.94 us). K1: fused prep + nn as separate
// concurrent blocks (r10). Prep: 32-j tile, 8 blocks/CU (r15), r11 main loop,
// dwordx4-packed readout with the verbatim per-dword swizzle formula (r16).
// nn: r3 vectorized scan. Open item: prep ~60 us, latency-bound (Little's
// law ~2.5 TB/s effective); compiler remat defeats deeper MLP at source level
// (r11/r12/r17). Hazards: readout-swizzle reorgs corrupt (r2/r9); per-block
// device fences on large grids catastrophic (r13).
__global__ __launch_bounds__(256) void k_prep_nn(const float* __restrict__ f,
        const float* __restrict__ pts, _Float16* __restrict__ fh,
        unsigned char* __restrict__ valid, int* __restrict__ vcnt_part,
        const int* __restrict__ aidx, int* __restrict__ pos_idx,
        unsigned char* __restrict__ valid_a, int* __restrict__ ticket) {
  __shared__ __align__(16) unsigned tile[4][32 * 32];   // 16 KB
  __shared__ float ssql[4][8][4];
  __shared__ float srn[32];
  int tid = threadIdx.x;

  if (blockIdx.x < 96) {
    // ------------------------- prep branch -------------------------
    int j0 = blockIdx.x * 32;
    int bn = blockIdx.y;
    int n = bn & 3;            // bn = b*N + n
    int jq = tid & 7;          // j-quad: j_local = 4*jq + {0..3}
    int dr = (tid >> 3) & 15;  // d-row group: rows 4*dr + {0..3} within dt
    int hh = tid >> 7;         // dt-pair half: dt = 2*hh + dtl

    f32x4 rv[2][4];
#pragma unroll
    for (int dtl = 0; dtl < 2; ++dtl) {
      int dt = 2 * hh + dtl;
      const float* fb = f + ((size_t)bn * D_ + dt * 64 + 4 * dr) * HW_ + j0 + 4 * jq;
      rv[dtl][0] = *(const f32x4*)&fb[0];
      rv[dtl][1] = *(const f32x4*)&fb[HW_];
      rv[dtl][2] = *(const f32x4*)&fb[2 * HW_];
      rv[dtl][3] = *(const f32x4*)&fb[3 * HW_];
    }

    float ssq0 = 0.f, ssq1 = 0.f, ssq2 = 0.f, ssq3 = 0.f;
    int p0 = 2 * dr;           // d-pair column within [0,32)
#pragma unroll
    for (int dtl = 0; dtl < 2; ++dtl) {
      int dt = 2 * hh + dtl;
      f32x4 r0 = rv[dtl][0], r1 = rv[dtl][1], r2 = rv[dtl][2], r3 = rv[dtl][3];
      ssq0 = fmaf(r0[0], r0[0], fmaf(r1[0], r1[0], fmaf(r2[0], r2[0], fmaf(r3[0], r3[0], ssq0))));
      ssq1 = fmaf(r0[1], r0[1], fmaf(r1[1], r1[1], fmaf(r2[1], r2[1], fmaf(r3[1], r3[1], ssq1))));
      ssq2 = fmaf(r0[2], r0[2], fmaf(r1[2], r1[2], fmaf(r2[2], r2[2], fmaf(r3[2], r3[2], ssq2))));
      ssq3 = fmaf(r0[3], r0[3], fmaf(r1[3], r1[3], fmaf(r2[3], r2[3], fmaf(r3[3], r3[3], ssq3))));
#pragma unroll
      for (int jj = 0; jj < 4; ++jj) {
        int jl = 4 * jq + jj;
        half2v h01, h23;
        h01[0] = (_Float16)r0[jj]; h01[1] = (_Float16)r1[jj];
        h23[0] = (_Float16)r2[jj]; h23[1] = (_Float16)r3[jj];
        unsigned u01 = __builtin_bit_cast(unsigned, h01);
        unsigned u23 = __builtin_bit_cast(unsigned, h23);
        uint2v w;
        if (jj & 1) { w[0] = u23; w[1] = u01; }   // odd jl: pair order swaps
        else        { w[0] = u01; w[1] = u23; }
        *(uint2v*)&tile[dt][jl * 32 + (p0 ^ (jl & 30))] = w;
      }
    }
    // reduce sumsq over dr&7 within wave (lanes differing in tid bits 3..5)
    ssq0 += __shfl_xor(ssq0, 8); ssq0 += __shfl_xor(ssq0, 16); ssq0 += __shfl_xor(ssq0, 32);
    ssq1 += __shfl_xor(ssq1, 8); ssq1 += __shfl_xor(ssq1, 16); ssq1 += __shfl_xor(ssq1, 32);
    ssq2 += __shfl_xor(ssq2, 8); ssq2 += __shfl_xor(ssq2, 16); ssq2 += __shfl_xor(ssq2, 32);
    ssq3 += __shfl_xor(ssq3, 8); ssq3 += __shfl_xor(ssq3, 16); ssq3 += __shfl_xor(ssq3, 32);
    if ((tid & 63) < 8) {
      int w = tid >> 6;        // w = (hh<<1) | (dr>>3): 4 partial groups
      ssql[w][jq][0] = ssq0; ssql[w][jq][1] = ssq1;
      ssql[w][jq][2] = ssq2; ssql[w][jq][3] = ssq3;
    }
    __syncthreads();
    if (tid < 32) {            // j = tid
      float s = ssql[0][tid >> 2][tid & 3] + ssql[1][tid >> 2][tid & 3]
              + ssql[2][tid >> 2][tid & 3] + ssql[3][tid >> 2][tid & 3];
      float r = 1.f / fmaxf(sqrtf(s), 1e-12f);
      srn[tid] = (n == 0) ? r * INV_T : r;
      size_t idx = (size_t)bn * HW_ + j0 + tid;
      const float* p = pts + idx * 3;
      float x = p[0], y = p[1], z = p[2];
      int v = (x * x + y * y + z * z) > 1e-12f ? 1 : 0;   // ||p|| > 1e-6
      valid[idx] = (unsigned char)v;
      unsigned long long mask = __ballot(v);
      if (tid == 0) vcnt_part[bn * NJB_ + blockIdx.x] = __popcll(mask);
    }
    __syncthreads();
    // readout (r16): thread (jr = tid>>3, c4 = tid&7) owns output dwords
    // 4*c4+{0..3} of row jr; each dword fetched with the VERBATIM proven
    // formula c ^ (jr & 31), scaled, packed, one dwordx4 store.
    unsigned* outw = (unsigned*)fh;
    int c4 = tid & 7;
    int jr = tid >> 3;         // 0..31
    float sc = srn[jr];
#pragma unroll
    for (int dt = 0; dt < 4; ++dt) {
      uint4v o;
#pragma unroll
      for (int i = 0; i < 4; ++i) {
        int c = 4 * c4 + i;
        unsigned u = tile[dt][jr * 32 + (c ^ (jr & 31))];
        half2v h = __builtin_bit_cast(half2v, u);
        half2v t;
        t[0] = (_Float16)((float)h[0] * sc);
        t[1] = (_Float16)((float)h[1] * sc);
        o[i] = __builtin_bit_cast(unsigned, t);
      }
      *(uint4v*)&outw[((size_t)bn * HW_ + j0 + jr) * (D_ / 2) + dt * 32 + 4 * c4] = o;
    }
  } else {
    // ------------------------- nn branch (r3 body verbatim) ---------------
    int gid = (blockIdx.x - 96) * 32 + blockIdx.y;   // 0..1535
    if (gid == 0 && tid == 0) *ticket = 0;
    int wave = tid >> 6, lane = tid & 63;
    int agrp = gid & 63;
    int b = (gid >> 6) & 7;
    int p = gid >> 9;
    int a = agrp * 4 + wave;
    int vv = p + 1;
    int col = aidx[(p * B_ + b) * A_ + a];
    const float* pi = pts + ((size_t)(b * N_) * HW_ + col) * 3;
    float ax = pi[0], ay = pi[1], az = pi[2];
    int vi = (ax * ax + ay * ay + az * az) > 1e-12f ? 1 : 0;
    const f32x4* pj4 = (const f32x4*)(pts + (size_t)(b * N_ + vv) * HW_ * 3);
    float best = INFINITY; int bidx = 0x7fffffff;
#pragma unroll 2
    for (int t = 0; t < HW_ / 256; ++t) {      // 12 iterations
      int jb = t * 256 + lane * 4;
      int base = t * 192 + lane * 3;           // float4 index: (jb*3)/4
      f32x4 q0 = pj4[base + 0];
      f32x4 q1 = pj4[base + 1];
      f32x4 q2 = pj4[base + 2];
      float px[4] = {q0[0], q0[3], q1[2], q2[1]};
      float py[4] = {q0[1], q1[0], q1[3], q2[2]};
      float pz[4] = {q0[2], q1[1], q2[0], q2[3]};
#pragma unroll
      for (int k = 0; k < 4; ++k) {
        float x = px[k], y = py[k], z = pz[k];
        int vj = (x * x + y * y + z * z) > 1e-12f;
        float dx = ax - x, dy = ay - y, dz = az - z;
        float dist = sqrtf(dx * dx + dy * dy + dz * dz);
        int j = jb + k;
        if (vj && (dist < best || (dist == best && j < bidx))) { best = dist; bidx = j; }
      }
    }
#pragma unroll
    for (int o = 32; o > 0; o >>= 1) {
      float ob = __shfl_xor(best, o);
      int oi = __shfl_xor(bidx, o);
      if (ob < best || (ob == best && oi < bidx)) { best = ob; bidx = oi; }
    }
    if (lane == 0) {
      int ai = (p * B_ + b) * A_ + a;
      pos_idx[ai] = (bidx == 0x7fffffff) ? 0 : bidx;
      valid_a[ai] = (best < 0.1f) && vi;
    }
  }
}

// ---------------------------------------------------------------------------
// K3: MFMA f16 GEMM, 128x128 tile, 4 waves (2x2 of 64x64), BK=64, dbuf LDS,
// LDS-transpose epilogue. r6 body verbatim (frozen).
#define STAGE_AB(KK, BUF) do {                                                 \
  _Pragma("unroll")                                                            \
  for (int cc = 0; cc < 4; ++cc) {                                             \
    const _Float16* srcA = fA + (size_t)colA[cc] * D_ + (KK) * 64 + gsw * 8;   \
    __builtin_amdgcn_global_load_lds(                                          \
        (const __attribute__((address_space(1))) void*)srcA,                   \
        (__attribute__((address_space(3))) void*)&As[BUF][(wid * 32 + cc * 8) * LDKH], \
        16, 0, 0);                                                             \
  }                                                                            \
  _Pragma("unroll")                                                            \
  for (int cc = 0; cc < 4; ++cc) {                                             \
    const _Float16* srcB = fB + (size_t)rowB[cc] * D_ + (KK) * 64 + gsw * 8;   \
    __builtin_amdgcn_global_load_lds(                                          \
        (const __attribute__((address_space(1))) void*)srcB,                   \
        (__attribute__((address_space(3))) void*)&Bs[BUF][(wid * 32 + cc * 8) * LDKH], \
        16, 0, 0);                                                             \
  }                                                                            \
} while (0)

__global__ __launch_bounds__(256) void k_gemm(const _Float16* __restrict__ fh,
    const int* __restrict__ aidx, const unsigned char* __restrict__ valid,
    const int* __restrict__ pos_idx, float* __restrict__ possim,
    float2* __restrict__ partials) {
  __shared__ __align__(16) char smem[65536];
  _Float16 (*As)[128 * LDKH] = reinterpret_cast<_Float16 (*)[128 * LDKH]>(smem);
  _Float16 (*Bs)[128 * LDKH] = reinterpret_cast<_Float16 (*)[128 * LDKH]>(smem + 32768);
  float (*scr)[132] = reinterpret_cast<float (*)[132]>(smem);   // reused post-K-loop

  int jt = blockIdx.x;
  int pbm = blockIdx.y;          // 0..47: pb*2 + mt
  int pb = pbm >> 1, mt = pbm & 1;
  int b = pb & 7, p = pb >> 3, v = p + 1;
  int tid = threadIdx.x;
  int wid = tid >> 6, lane = tid & 63;   // 4 waves
  int wr = wid >> 1, wc = wid & 1;       // 2x2 of 64x64
  int j0 = jt * 128;
  const _Float16* fA = fh + (size_t)(b * N_) * HW_ * D_;        // view 0
  const _Float16* fB = fh + (size_t)(b * N_ + v) * HW_ * D_;    // view v

  // staging: lane -> (row offset rl = lane>>3, granule gl = lane&7),
  // source granule pre-swizzled: gsw = gl ^ rl = g ^ (row&7).
  int rl = lane >> 3;
  int gl = lane & 7;
  int gsw = gl ^ rl;
  int colA[4];
#pragma unroll
  for (int c = 0; c < 4; ++c)
    colA[c] = aidx[(p * B_ + b) * A_ + mt * 128 + wid * 32 + c * 8 + rl];
  int rowB[4];
#pragma unroll
  for (int c = 0; c < 4; ++c) rowB[c] = j0 + wid * 32 + c * 8 + rl;

  f32x4 acc[4][4];
#pragma unroll
  for (int m = 0; m < 4; ++m)
#pragma unroll
    for (int n = 0; n < 4; ++n) acc[m][n] = (f32x4)0.f;

  int kg = lane >> 4;        // k-granule 0..3
  int fr = lane & 15;        // fragment row

  STAGE_AB(0, 0);
  __syncthreads();           // drains vmcnt(0): buf0 ready

#pragma unroll
  for (int kk = 0; kk < 4; ++kk) {
    const int cur = kk & 1;
    if (kk < 3) STAGE_AB(kk + 1, cur ^ 1);   // issue-early: hides under MFMA
#pragma unroll
    for (int s = 0; s < 2; ++s) {
      half8 af[4], bf[4];
      int G = s * 4 + kg;
#pragma unroll
      for (int m = 0; m < 4; ++m) {
        int row = wr * 64 + m * 16 + fr;
        af[m] = *(half8*)&As[cur][row * LDKH + ((G ^ (row & 7)) << 3)];
      }
#pragma unroll
      for (int n = 0; n < 4; ++n) {
        int row = wc * 64 + n * 16 + fr;
        bf[n] = *(half8*)&Bs[cur][row * LDKH + ((G ^ (row & 7)) << 3)];
      }
      __builtin_amdgcn_s_setprio(1);
#pragma unroll
      for (int m = 0; m < 4; ++m)
#pragma unroll
        for (int n = 0; n < 4; ++n)
          acc[m][n] = __builtin_amdgcn_mfma_f32_16x16x32_f16(af[m], bf[n], acc[m][n], 0, 0, 0);
      __builtin_amdgcn_s_setprio(0);
    }
    if (kk < 3) __syncthreads();   // drains prefetch vmcnt; next buf ready
  }

  // ---- epilogue (LDS-transpose, sequential per-thread reduction) ----
  __syncthreads();   // all As/Bs reads retired -> LDS reusable as scratch

  int vrow = b * N_ + v;
  int a_loc = tid >> 1, h = tid & 1;          // anchor 0..127, j-half 0/1
  int aig = pb * A_ + mt * 128 + a_loc;
  int pidx = pos_idx[aig];

#pragma unroll
  for (int pss = 0; pss < 2; ++pss) {
    if (wc == pss) {
      // dump this wave's 64x64 acc tile: value (m,n,reg) is anchor
      // wr*64+m*16+kg*4+reg, local column n*16+fr within the pss 64-j half
#pragma unroll
      for (int m = 0; m < 4; ++m)
#pragma unroll
        for (int n = 0; n < 4; ++n)
          *(f32x4*)&scr[n * 16 + fr][wr * 64 + m * 16 + kg * 4] = acc[m][n];
    }
    __syncthreads();
    int jbase = j0 + pss * 64 + h * 32;
    const unsigned* vp = (const unsigned*)(valid + (size_t)vrow * HW_ + jbase);
    unsigned vw[8];
#pragma unroll
    for (int w = 0; w < 8; ++w) vw[w] = vp[w];
    float vv[32];
#pragma unroll
    for (int jj = 0; jj < 32; ++jj) vv[jj] = scr[h * 32 + jj][a_loc];
    float mx = -INFINITY;
#pragma unroll
    for (int jj = 0; jj < 32; ++jj) {
      if ((vw[jj >> 2] >> ((jj & 3) * 8)) & 0xff) mx = fmaxf(mx, vv[jj]);
      if (jbase + jj == pidx) possim[aig] = vv[jj];
    }
    float S = 0.f;
#pragma unroll
    for (int jj = 0; jj < 32; ++jj) {
      if ((vw[jj >> 2] >> ((jj & 3) * 8)) & 0xff) S += __expf(vv[jj] - mx);
    }
    // merge the two 32-j halves of this anchor (partner thread = tid^1)
    float am = fmaxf(mx, __shfl_xor(mx, 1));
    float Ss = (mx == am) ? S : S * __expf(mx - am);
    Ss += __shfl_xor(Ss, 1);
    if (h == 0) partials[(size_t)aig * NJT2_ + (jt * 2 + pss)] = make_float2(am, Ss);
    __syncthreads();   // pass-1 reads done before pass-2 overwrites scratch
  }
}

// ---------------------------------------------------------------------------
// K4: merge partial LSEs (4 threads/anchor), per-(pair,batch) reduction +
// include; last block (device ticket) computes the final scalar. (r6 body;
// vcnt loops at NJB_=96)
__global__ __launch_bounds__(1024) void k_merge(const float2* __restrict__ partials,
    const float* __restrict__ possim, const unsigned char* __restrict__ valid_a,
    const int* __restrict__ vcnt_part, float* __restrict__ lossb,
    int* __restrict__ incb, int* __restrict__ ticket, float* __restrict__ out) {
  int pb = blockIdx.x;
  int b = pb & 7, p = pb >> 3;
  int tid = threadIdx.x;
  int a = tid >> 2, q = tid & 3;
  int ai = pb * A_ + a;

  __shared__ float ss[16]; __shared__ int sc[16];
  __shared__ int v0c, vvc;
  if (tid == 0) { v0c = 0; vvc = 0; }
  __syncthreads();
  if (tid < NJB_) atomicAdd(&v0c, vcnt_part[(b * N_ + 0) * NJB_ + tid]);
  else if (tid < 2 * NJB_) atomicAdd(&vvc, vcnt_part[(b * N_ + p + 1) * NJB_ + (tid - NJB_)]);

  // each thread: 12 (m,S) pairs = 6 float4, contiguous 96 B
  const float4* pt = (const float4*)partials + (size_t)ai * 24 + q * 6;
  float4 vv4[6];
#pragma unroll
  for (int i = 0; i < 6; ++i) vv4[i] = pt[i];
  float mx = -INFINITY;
#pragma unroll
  for (int i = 0; i < 6; ++i) { mx = fmaxf(mx, vv4[i].x); mx = fmaxf(mx, vv4[i].z); }
  float S = 0.f;
  if (mx != -INFINITY) {
#pragma unroll
    for (int i = 0; i < 6; ++i) {
      S += vv4[i].y * __expf(vv4[i].x - mx);
      S += vv4[i].w * __expf(vv4[i].z - mx);
    }
  }
  // merge across the 4 lanes of this anchor
  float am = mx;
#pragma unroll
  for (int o = 1; o < 4; o <<= 1) am = fmaxf(am, __shfl_xor(am, o));
  float Sg = S * ((mx == am) ? 1.f : __expf(mx - am));
#pragma unroll
  for (int o = 1; o < 4; o <<= 1) Sg += __shfl_xor(Sg, o);

  float contrib = 0.f; int cnt = 0;
  if (q == 0) {
    float lse = (am == -INFINITY) ? -INFINITY : am + logf(Sg);
    if (valid_a[ai]) { contrib = lse - possim[ai]; cnt = 1; }
  }
  // wave reduce (leads are lanes with (lane&3)==0)
#pragma unroll
  for (int o = 4; o < 64; o <<= 1) {
    contrib += __shfl_xor(contrib, o);
    cnt += __shfl_xor(cnt, o);
  }
  if ((tid & 63) == 0) { ss[tid >> 6] = contrib; sc[tid >> 6] = cnt; }
  __syncthreads();
  if (tid == 0) {
    float s = 0.f; int c = 0;
#pragma unroll
    for (int i = 0; i < 16; ++i) { s += ss[i]; c += sc[i]; }
    float lb = s / (float)(c > 1 ? c : 1);
    int inc = (c >= 5) && (v0c >= 10) && (vvc >= 10);
    lossb[pb] = lb;
    incb[pb] = inc;
    __threadfence();
    int old = atomicAdd(ticket, 1);
    if (old == NP_ * B_ - 1) {
      __threadfence();
      float total = 0.f;
      for (int pp = 0; pp < NP_; ++pp) {
        float sacc = 0.f; int n = 0;
        for (int bb = 0; bb < B_; ++bb)
          if (incb[pp * B_ + bb]) { sacc += lossb[pp * B_ + bb]; ++n; }
        total += (n > 0) ? sacc / (float)n : 0.f;
      }
      out[0] = total / (float)NP_;
    }
  }
}

// ---------------------------------------------------------------------------
extern "C" void kernel_launch(void* const* d_in, const int* in_sizes, int n_in,
                              void* d_out, int out_size, void* d_ws, size_t ws_size,
                              hipStream_t stream) {
  const float* f   = (const float*)d_in[0];   // [B,N,D,H,W] fp32
  const float* pts = (const float*)d_in[1];   // [B,N,H,W,3] fp32
  const int* aidx  = (const int*)d_in[2];     // [NP,B,A] int32
  float* out = (float*)d_out;

  char* ws = (char*)d_ws;
  _Float16* fh          = (_Float16*)(ws);                    // 32*3072*256*2 = 50,331,648
  unsigned char* valid  = (unsigned char*)(ws + 50331648);    // 98,304
  int* pos_idx          = (int*)(ws + 50429952);              // 24,576
  unsigned char* valid_a= (unsigned char*)(ws + 50454528);    // 6,144
  float* possim         = (float*)(ws + 50460672);            // 24,576
  float* lossb          = (float*)(ws + 50485248);            // 96 (pad to 128)
  int* incb             = (int*)(ws + 50485376);              // 96 (pad to 128)
  float2* partials      = (float2*)(ws + 50485504);           // 6144*48*8 = 2,359,296
  int* vcnt_part        = (int*)(ws + 52844800);              // 32*96*4 = 12,288
  int* ticket           = (int*)(ws + 52857088);              // 4
  // total ws usage: 52,857,092 bytes

  k_prep_nn<<<dim3(144, 32), 256, 0, stream>>>(f, pts, fh, valid, vcnt_part,
                                               aidx, pos_idx, valid_a, ticket);
  k_gemm<<<dim3(24, NP_ * B_ * 2), 256, 0, stream>>>(fh, aidx, valid, pos_idx, possim, partials);
  k_merge<<<NP_ * B_, 1024, 0, stream>>>(partials, possim, valid_a, vcnt_part, lossb, incb, ticket, out);
}